// Round 11
// baseline (23880.608 us; speedup 1.0000x reference)
//
#include <hip/hip_runtime.h>
#include <cstdint>

#define NBLK 128
#define BLOCK 1024
#define ROWS 32            // hidden rows per block: 128*32 = 4096
#define HDIM 4096
#define IDIM 64
#define ODIM 16
#define TSTEPS 4096
#define PAD 576            // 18 groups * 32 slots (bank-dealt ELL)
#define GMAX 18
#define RNDS 9             // fixed-trip: covers gu <= 18; pads gather s_lds[0]*0
#define LEAK 0.9f
#define SU 11              // s units per producer: 3 vals + tag each (unit 10: 2 vals)
#define SUS 12             // s unit stride per producer (pad to 192B)
#define YU 8               // y units per producer: 2 vals + tag + pad

typedef float f32x4 __attribute__((ext_vector_type(4)));

// zero the tagged-exchange region every launch (tags use ==, so 0 never matches)
__global__ void init_ws(float* ws) {
    int i = blockIdx.x * blockDim.x + threadIdx.x;
    if (i < (2 * NBLK * SUS + 2 * NBLK * YU) * 4) ws[i] = 0.0f;
}

// min 4 waves/EU = 16 waves/CU = 1 block/CU -> VGPR cap 128 (not 64):
// keeps the preloaded ELL registers out of scratch.
__global__ __launch_bounds__(BLOCK, 4) void esn_kernel(
    const float* __restrict__ X,     // [T][I]
    const float* __restrict__ Win,   // [H][I]
    const float* __restrict__ Wres,  // [H][H]
    const float* __restrict__ bvec,  // [H]
    const float* __restrict__ Wfb,   // [H][O]
    const float* __restrict__ Wout,  // [O][H]
    float* __restrict__ out,         // results [T][O] then outputs [T][H]
    float* __restrict__ sx,          // [2][NBLK][SUS] tagged f32x4 units (s exchange)
    float* __restrict__ yx)          // [2][NBLK][YU]  tagged f32x4 units (y partials)
{
    __shared__ float          ell_val[ROWS][PAD];   // 73728 B (build-time only)
    __shared__ unsigned short ell_idx[ROWS][PAD];   // 36864 B (build-time only)
    __shared__ __align__(16) float s_lds[HDIM];     // 16384 B
    __shared__ float          win_lds[ROWS][IDIM];
    __shared__ float          wfb_lds[ROWS][ODIM];
    __shared__ __align__(8)  float wout_lds[ROWS][ODIM]; // [r][o]
    __shared__ float          b_lds[ROWS];
    __shared__ float          x_lds[IDIM];
    __shared__ float          y_lds[ODIM];
    __shared__ __align__(16) float snew_lds[ROWS];
    __shared__ int            nnz_lds[ROWS];
    __shared__ unsigned short bankCnt[ROWS][32];
    __shared__ unsigned short grpCnt[ROWS][GMAX];

    const int tid   = threadIdx.x;
    const int blk   = blockIdx.x;
    const int rbase = blk * ROWS;
    const int rowB  = tid >> 5;        // 0..31
    const int lB    = tid & 31;

    // ---- pass 0: zero ELL + counters ----
    for (int i = tid; i < ROWS * PAD; i += BLOCK) {
        ell_val[i / PAD][i % PAD] = 0.0f;
        ell_idx[i / PAD][i % PAD] = 0;
    }
    for (int i = tid; i < ROWS * 32; i += BLOCK) bankCnt[i >> 5][i & 31] = 0;
    for (int i = tid; i < ROWS * GMAX; i += BLOCK) grpCnt[i / GMAX][i % GMAX] = 0;

    // ---- pass 1 (parallel): nnz per row ----
    {
        const int wave = tid >> 6, lane = tid & 63;
        for (int rr = wave * 2; rr < wave * 2 + 2; ++rr) {
            const float* wrow = Wres + (size_t)(rbase + rr) * HDIM;
            int cnt = 0;
            for (int c0 = 0; c0 < HDIM; c0 += 64)
                cnt += __popcll(__ballot(wrow[c0 + lane] != 0.0f));
            if (lane == 0) nnz_lds[rr] = cnt < PAD ? cnt : PAD;
        }
    }
    __syncthreads();

    // ---- pass 2 (serial per row, deterministic): bank-balanced deal ----
    {
        const int wave = tid >> 6, lane = tid & 63;
        if (lane == 0 || lane == 32) {
            const int row = wave * 2 + (lane >> 5);
            const int nz  = nnz_lds[row];
            int gu = (nz + 31) >> 5;
            if (gu < 1) gu = 1;
            if (gu > GMAX) gu = GMAX;
            const float* wrow = Wres + (size_t)(rbase + row) * HDIM;
            int placed = 0;
            for (int c = 0; c < HDIM && placed < nz; ++c) {
                const float w = wrow[c];
                if (w != 0.0f) {
                    const int b = c & 31;
                    const int r = bankCnt[row][b];
                    bankCnt[row][b] = (unsigned short)(r + 1);
                    int g = r % gu;
                    int p = grpCnt[row][g];
                    int guard = 0;
                    while (p >= 32 && guard < GMAX) {
                        g = (g + 1 == gu) ? 0 : g + 1;
                        p = grpCnt[row][g];
                        ++guard;
                    }
                    if (p >= 32) break;
                    grpCnt[row][g] = (unsigned short)(p + 1);
                    const int slot = ((g >> 1) << 6) + 2 * p + (g & 1);
                    ell_val[row][slot] = w;
                    ell_idx[row][slot] = (unsigned short)c;
                    ++placed;
                }
            }
        }
    }

    // ---- small weights into LDS ----
    for (int i = tid; i < ROWS * IDIM; i += BLOCK)
        win_lds[i >> 6][i & 63] = Win[(size_t)(rbase + (i >> 6)) * IDIM + (i & 63)];
    for (int i = tid; i < ROWS * ODIM; i += BLOCK)
        wfb_lds[i >> 4][i & 15] = Wfb[(size_t)(rbase + (i >> 4)) * ODIM + (i & 15)];
    for (int i = tid; i < ROWS * ODIM; i += BLOCK)   // [r][o] = Wout[o][rbase+r]
        wout_lds[i >> 4][i & 15] = Wout[(size_t)(i & 15) * HDIM + rbase + (i >> 4)];
    if (tid < ROWS) b_lds[tid] = bvec[rbase + tid];

    // ---- prologue: s_{-1}=0, y_{-1}=0, x_0 ----
    for (int i = tid; i < HDIM; i += BLOCK) s_lds[i] = 0.0f;
    if (tid < ODIM) y_lds[tid] = 0.0f;
    if (tid >= 64 && tid < 128) x_lds[tid - 64] = X[tid - 64];
    __syncthreads();

    // ---- preload ELL slots + input weights into REGISTERS (constant over t) ----
    float2   rv[RNDS];
    unsigned ri[RNDS];
    #pragma unroll
    for (int k = 0; k < RNDS; ++k) {
        const int e = (k << 6) + (lB << 1);
        rv[k] = *(const float2*)&ell_val[rowB][e];
        ri[k] = *(const unsigned*)&ell_idx[rowB][e];   // packed ushort2
    }
    const float winA = win_lds[rowB][lB];
    const float winB = win_lds[rowB][lB + 32];
    const float wfbv = (lB < ODIM) ? wfb_lds[rowB][lB] : 0.0f;
    const float bias = b_lds[rowB];

    float* out_res = out;
    float* out_s   = out + (size_t)TSTEPS * ODIM;

    const int wv = tid >> 6;
    const int ln = tid & 63;

    for (int t = 0; t < TSTEPS; ++t) {
        const unsigned tu = (unsigned)(t + 1);
        const float tagf = __uint_as_float(tu);

        // ---- phase B: pre = Wres@s + Win@x + Wfb@y + b ; s_new ----
        {
            float a0 = 0.0f, a1 = 0.0f;
            #pragma unroll
            for (int k = 0; k < RNDS; ++k) {
                a0 += rv[k].x * s_lds[ri[k] & 0xffffu];
                a1 += rv[k].y * s_lds[ri[k] >> 16];
            }
            float acc = a0 + a1;
            acc += winA * x_lds[lB] + winB * x_lds[lB + 32];
            if (lB < ODIM) acc += wfbv * y_lds[lB];
            acc += __shfl_xor(acc, 16, 32);
            acc += __shfl_xor(acc, 8, 32);
            acc += __shfl_xor(acc, 4, 32);
            acc += __shfl_xor(acc, 2, 32);
            acc += __shfl_xor(acc, 1, 32);
            if (lB == 0) {
                const float pre = acc + bias;
                snew_lds[rowB] = (1.0f - LEAK) * s_lds[rbase + rowB] + LEAK * tanhf(pre);
            }
        }
        __syncthreads();   // B-sync: snew_lds ready; s/x/y_lds free

        if (wv == 0) {
            // ---- publish: tagged s units, y units, out_s ----
            if (ln >= 16 && ln < 16 + SU) {            // 11 lanes: s units
                const int j  = ln - 16;
                const int b0 = 3 * j;
                const int b1 = (3 * j + 1 < 32) ? 3 * j + 1 : 31;
                const int b2 = (3 * j + 2 < 32) ? 3 * j + 2 : 31;
                f32x4 v;
                v.x = snew_lds[b0]; v.y = snew_lds[b1]; v.z = snew_lds[b2]; v.w = tagf;
                float* dst = sx + (((size_t)(t & 1) * NBLK + blk) * SUS + j) * 4;
                asm volatile("global_store_dwordx4 %0, %1, off sc0 sc1"
                             :: "v"(dst), "v"(v) : "memory");
            }
            if (ln < YU) {                             // 8 lanes: y partial units
                float a0 = 0.0f, a1 = 0.0f;
                #pragma unroll
                for (int r = 0; r < ROWS; ++r) {
                    const float2 w = *(const float2*)&wout_lds[r][2 * ln];
                    a0 += w.x * snew_lds[r];
                    a1 += w.y * snew_lds[r];
                }
                f32x4 v; v.x = a0; v.y = a1; v.z = tagf; v.w = 0.0f;
                float* dst = yx + (((size_t)(t & 1) * NBLK + blk) * YU + ln) * 4;
                asm volatile("global_store_dwordx4 %0, %1, off sc0 sc1"
                             :: "v"(dst), "v"(v) : "memory");
            }
            if (ln >= 32 && ln < 40) {                 // 8 lanes: out_s (write-only)
                const int j = ln - 32;
                *(f32x4*)(out_s + (size_t)t * HDIM + rbase + j * 4) =
                    *(const f32x4*)&snew_lds[j * 4];
            }
        } else if (wv == 1) {
            // ---- y-reduce: poll all 128 producers' tagged units, butterfly ----
            if (t + 1 < TSTEPS) x_lds[ln] = X[(size_t)(t + 1) * IDIM + ln];
            const int u  = ln & 7;
            const int pg = ln >> 3;                    // 8 producer groups of 16
            const float* yb = yx + (size_t)(t & 1) * NBLK * YU * 4;
            f32x4 w0,w1,w2,w3,w4,w5,w6,w7,w8,w9,w10,w11,w12,w13,w14,w15;
            for (;;) {
                #define YL(i) asm volatile("global_load_dwordx4 %0, %1, off sc0 sc1" \
                    : "=v"(w##i) : "v"(yb + (((pg << 4) + i) * YU + u) * 4));
                YL(0) YL(1) YL(2) YL(3) YL(4) YL(5) YL(6) YL(7)
                YL(8) YL(9) YL(10) YL(11) YL(12) YL(13) YL(14) YL(15)
                #undef YL
                asm volatile("s_waitcnt vmcnt(0)" ::: "memory");
                __builtin_amdgcn_sched_barrier(0);
                bool ok = __float_as_uint(w0.z) == tu  && __float_as_uint(w1.z) == tu
                       && __float_as_uint(w2.z) == tu  && __float_as_uint(w3.z) == tu
                       && __float_as_uint(w4.z) == tu  && __float_as_uint(w5.z) == tu
                       && __float_as_uint(w6.z) == tu  && __float_as_uint(w7.z) == tu
                       && __float_as_uint(w8.z) == tu  && __float_as_uint(w9.z) == tu
                       && __float_as_uint(w10.z) == tu && __float_as_uint(w11.z) == tu
                       && __float_as_uint(w12.z) == tu && __float_as_uint(w13.z) == tu
                       && __float_as_uint(w14.z) == tu && __float_as_uint(w15.z) == tu;
                if (__all(ok)) break;
            }
            float acc0 = ((w0.x + w1.x) + (w2.x + w3.x)) + ((w4.x + w5.x) + (w6.x + w7.x))
                       + ((w8.x + w9.x) + (w10.x + w11.x)) + ((w12.x + w13.x) + (w14.x + w15.x));
            float acc1 = ((w0.y + w1.y) + (w2.y + w3.y)) + ((w4.y + w5.y) + (w6.y + w7.y))
                       + ((w8.y + w9.y) + (w10.y + w11.y)) + ((w12.y + w13.y) + (w14.y + w15.y));
            acc0 += __shfl_xor(acc0, 8);  acc1 += __shfl_xor(acc1, 8);
            acc0 += __shfl_xor(acc0, 16); acc1 += __shfl_xor(acc1, 16);
            acc0 += __shfl_xor(acc0, 32); acc1 += __shfl_xor(acc1, 32);
            if (ln < 8) {
                if (t + 1 < TSTEPS) { y_lds[2 * u] = acc0; y_lds[2 * u + 1] = acc1; }
                if (blk == 0) {
                    out_res[(size_t)t * ODIM + 2 * u]     = acc0;
                    out_res[(size_t)t * ODIM + 2 * u + 1] = acc1;
                }
            }
        } else {
            // ---- s-consumer: poll tagged units of this wave's producer slice ----
            if (t + 1 < TSTEPS) {
                const int wi    = wv - 2;                        // 0..13
                const int start = (wi < 2) ? wi * 10 : 20 + (wi - 2) * 9;
                const int count = (wi < 2) ? 10 : 9;             // 2*10 + 12*9 = 128
                const int U     = count * SU;
                const float* sb = sx + (size_t)(t & 1) * NBLK * SUS * 4;
                const int g0 = ln, g1 = ln + 64;
                const int p0 = g0 / SU, u0 = g0 - p0 * SU;
                const bool h1 = g1 < U;
                const int p1 = g1 / SU, u1 = g1 - p1 * SU;
                const float* a0p = sb + (((start + p0) * SUS) + u0) * 4;
                const float* a1p = sb + (((start + p1) * SUS) + u1) * 4;
                f32x4 v0, v1;
                for (;;) {
                    asm volatile("global_load_dwordx4 %0, %1, off sc0 sc1"
                                 : "=v"(v0) : "v"(a0p));
                    if (h1)
                        asm volatile("global_load_dwordx4 %0, %1, off sc0 sc1"
                                     : "=v"(v1) : "v"(a1p));
                    asm volatile("s_waitcnt vmcnt(0)" ::: "memory");
                    __builtin_amdgcn_sched_barrier(0);
                    bool ok = (__float_as_uint(v0.w) == tu) &&
                              (!h1 || __float_as_uint(v1.w) == tu);
                    if (__all(ok)) break;
                }
                {
                    const int c0 = (start + p0) * 32 + u0 * 3;
                    s_lds[c0] = v0.x; s_lds[c0 + 1] = v0.y;
                    if (u0 != SU - 1) s_lds[c0 + 2] = v0.z;
                }
                if (h1) {
                    const int c1 = (start + p1) * 32 + u1 * 3;
                    s_lds[c1] = v1.x; s_lds[c1 + 1] = v1.y;
                    if (u1 != SU - 1) s_lds[c1 + 2] = v1.z;
                }
            }
        }
        __syncthreads();   // A-sync: s/x/y for t+1 ready
    }
}

extern "C" void kernel_launch(void* const* d_in, const int* in_sizes, int n_in,
                              void* d_out, int out_size, void* d_ws, size_t ws_size,
                              hipStream_t stream) {
    (void)in_sizes; (void)n_in; (void)out_size; (void)ws_size;
    const float* X    = (const float*)d_in[0];
    const float* Win  = (const float*)d_in[1];
    const float* Wres = (const float*)d_in[2];
    const float* b    = (const float*)d_in[3];
    const float* Wfb  = (const float*)d_in[4];
    const float* Wout = (const float*)d_in[5];
    float* out = (float*)d_out;
    float* sx  = (float*)d_ws;                          // 2*128*12*16B = 48 KiB
    float* yx  = (float*)d_ws + 2 * NBLK * SUS * 4;     // 2*128*8*16B  = 32 KiB

    const int words = (2 * NBLK * SUS + 2 * NBLK * YU) * 4;
    init_ws<<<(words + 255) / 256, 256, 0, stream>>>((float*)d_ws);
    esn_kernel<<<NBLK, BLOCK, 0, stream>>>(X, Win, Wres, b, Wfb, Wout, out, sx, yx);
}

// Round 12
// 21427.806 us; speedup vs baseline: 1.1145x; 1.1145x over previous
//
#include <hip/hip_runtime.h>
#include <cstdint>

#define NBLK 128
#define BLOCK 1024
#define ROWS 32            // hidden rows per block: 128*32 = 4096
#define HDIM 4096
#define IDIM 64
#define ODIM 16
#define TSTEPS 4096
#define PAD 576            // 18 groups * 32 slots (bank-dealt ELL)
#define GMAX 18
#define LEAK 0.9f
#define SU 11              // s units per producer: 3 vals + tag each (unit 10: 2 vals)
#define SUS 12             // s unit stride per producer (pad to 192B)
#define YU 8               // y units per producer: 2 vals + tag + pad

typedef float f32x4 __attribute__((ext_vector_type(4)));

// zero the tagged-exchange region every launch (tags use ==, so 0 never matches)
__global__ void init_ws(float* ws) {
    int i = blockIdx.x * blockDim.x + threadIdx.x;
    if (i < (2 * NBLK * SUS + 2 * NBLK * YU) * 4) ws[i] = 0.0f;
}

__global__ __launch_bounds__(BLOCK) void esn_kernel(
    const float* __restrict__ X,     // [T][I]
    const float* __restrict__ Win,   // [H][I]
    const float* __restrict__ Wres,  // [H][H]
    const float* __restrict__ bvec,  // [H]
    const float* __restrict__ Wfb,   // [H][O]
    const float* __restrict__ Wout,  // [O][H]
    float* __restrict__ out,         // results [T][O] then outputs [T][H]
    float* __restrict__ sx,          // [2][NBLK][SUS] tagged f32x4 units (s exchange)
    float* __restrict__ yx)          // [2][NBLK][YU]  tagged f32x4 units (y partials)
{
    __shared__ float          ell_val[ROWS][PAD];   // 73728 B
    __shared__ unsigned short ell_idx[ROWS][PAD];   // 36864 B
    __shared__ __align__(16) float s_lds[2][HDIM];  // 32768 B (double buffer: no B-sync)
    __shared__ float          win_lds[ROWS][IDIM];  //  8192 B
    __shared__ float          wfb_lds[ROWS][ODIM];  //  2048 B
    __shared__ __align__(8)  float wout_lds[ROWS][ODIM]; // 2048 B ([r][o])
    __shared__ float          b_lds[ROWS];
    __shared__ float          x_lds[2][IDIM];       //  512 B (double buffer)
    __shared__ float          y_lds[2][ODIM];       //  128 B (double buffer)
    __shared__ __align__(16) float snew_lds[ROWS];
    __shared__ unsigned       snflag[ROWS];         // per-row phase-B completion
    __shared__ int            nnz_lds[ROWS];
    __shared__ int            rnds_lds[ROWS];
    __shared__ unsigned char  bankCnt[ROWS][32];    // 1024 B (build only)
    __shared__ unsigned char  grpCnt[ROWS][GMAX];   //  576 B (build only)

    const int tid   = threadIdx.x;
    const int blk   = blockIdx.x;
    const int rbase = blk * ROWS;
    const int rowB  = tid >> 5;        // 0..31
    const int lB    = tid & 31;
    const int wv    = tid >> 6;        // 0..15
    const int ln    = tid & 63;

    // ---- pass 0: zero ELL + counters + flags ----
    for (int i = tid; i < ROWS * PAD; i += BLOCK) {
        ell_val[i / PAD][i % PAD] = 0.0f;
        ell_idx[i / PAD][i % PAD] = 0;
    }
    for (int i = tid; i < ROWS * 32; i += BLOCK) bankCnt[i >> 5][i & 31] = 0;
    for (int i = tid; i < ROWS * GMAX; i += BLOCK) grpCnt[i / GMAX][i % GMAX] = 0;
    if (tid < ROWS) snflag[tid] = 0u;

    // ---- pass 1 (parallel): nnz per row ----
    {
        for (int rr = wv * 2; rr < wv * 2 + 2; ++rr) {
            const float* wrow = Wres + (size_t)(rbase + rr) * HDIM;
            int cnt = 0;
            for (int c0 = 0; c0 < HDIM; c0 += 64)
                cnt += __popcll(__ballot(wrow[c0 + ln] != 0.0f));
            if (ln == 0) {
                int nz = cnt < PAD ? cnt : PAD;
                nnz_lds[rr] = nz;
                int gu = (nz + 31) >> 5;
                if (gu < 1) gu = 1;
                if (gu > GMAX) gu = GMAX;
                rnds_lds[rr] = (gu + 1) >> 1;
            }
        }
    }
    __syncthreads();

    // ---- pass 2 (serial per row, deterministic): bank-balanced deal ----
    {
        if (ln == 0 || ln == 32) {
            const int row = wv * 2 + (ln >> 5);
            const int nz  = nnz_lds[row];
            int gu = (nz + 31) >> 5;
            if (gu < 1) gu = 1;
            if (gu > GMAX) gu = GMAX;
            const float* wrow = Wres + (size_t)(rbase + row) * HDIM;
            int placed = 0;
            for (int c = 0; c < HDIM && placed < nz; ++c) {
                const float w = wrow[c];
                if (w != 0.0f) {
                    const int b = c & 31;
                    const int r = bankCnt[row][b];
                    bankCnt[row][b] = (unsigned char)(r + 1);
                    int g = r % gu;
                    int p = grpCnt[row][g];
                    int guard = 0;
                    while (p >= 32 && guard < GMAX) {
                        g = (g + 1 == gu) ? 0 : g + 1;
                        p = grpCnt[row][g];
                        ++guard;
                    }
                    if (p >= 32) break;
                    grpCnt[row][g] = (unsigned char)(p + 1);
                    const int slot = ((g >> 1) << 6) + 2 * p + (g & 1);
                    ell_val[row][slot] = w;
                    ell_idx[row][slot] = (unsigned short)c;
                    ++placed;
                }
            }
        }
    }

    // ---- small weights into LDS ----
    for (int i = tid; i < ROWS * IDIM; i += BLOCK)
        win_lds[i >> 6][i & 63] = Win[(size_t)(rbase + (i >> 6)) * IDIM + (i & 63)];
    for (int i = tid; i < ROWS * ODIM; i += BLOCK)
        wfb_lds[i >> 4][i & 15] = Wfb[(size_t)(rbase + (i >> 4)) * ODIM + (i & 15)];
    for (int i = tid; i < ROWS * ODIM; i += BLOCK)   // [r][o] = Wout[o][rbase+r]
        wout_lds[i >> 4][i & 15] = Wout[(size_t)(i & 15) * HDIM + rbase + (i >> 4)];
    if (tid < ROWS) b_lds[tid] = bvec[rbase + tid];

    // ---- prologue: s_{-1}=0, y_{-1}=0, x_0 ----
    for (int i = tid; i < HDIM; i += BLOCK) s_lds[0][i] = 0.0f;
    if (tid < ODIM) y_lds[0][tid] = 0.0f;
    if (tid >= 64 && tid < 128) x_lds[0][tid - 64] = X[tid - 64];
    __syncthreads();

    float* out_res = out;
    float* out_s   = out + (size_t)TSTEPS * ODIM;
    const int RB = rnds_lds[rowB];

    for (int t = 0; t < TSTEPS; ++t) {
        const unsigned tu = (unsigned)(t + 1);
        const float tagf = __uint_as_float(tu);
        const int cur = t & 1, nxt = cur ^ 1;

        // ---- phase B: pre = Wres@s + Win@x + Wfb@y + b ; s_new; per-row flag ----
        {
            const float* sc = s_lds[cur];
            float a0 = 0.0f, a1 = 0.0f;
            for (int k = 0; k < RB; ++k) {
                const int e = (k << 6) + (lB << 1);
                const float2  v  = *(const float2*)&ell_val[rowB][e];
                const ushort2 ix = *(const ushort2*)&ell_idx[rowB][e];
                a0 += v.x * sc[ix.x];
                a1 += v.y * sc[ix.y];
            }
            float acc = a0 + a1;
            acc += win_lds[rowB][lB] * x_lds[cur][lB]
                 + win_lds[rowB][lB + 32] * x_lds[cur][lB + 32];
            if (lB < ODIM) acc += wfb_lds[rowB][lB] * y_lds[cur][lB];
            acc += __shfl_xor(acc, 16, 32);
            acc += __shfl_xor(acc, 8, 32);
            acc += __shfl_xor(acc, 4, 32);
            acc += __shfl_xor(acc, 2, 32);
            acc += __shfl_xor(acc, 1, 32);
            if (lB == 0) {
                const float pre = acc + b_lds[rowB];
                snew_lds[rowB] = (1.0f - LEAK) * sc[rbase + rowB] + LEAK * tanhf(pre);
                __hip_atomic_store(&snflag[rowB], tu, __ATOMIC_RELEASE,
                                   __HIP_MEMORY_SCOPE_WORKGROUP);   // row done
            }
        }
        // NO block-wide B-sync: consumers go straight to polling.

        if (wv == 0) {
            // ---- wait own block's 32 rows (LDS flags), then publish ----
            for (;;) {
                unsigned f = (ln < ROWS)
                    ? __hip_atomic_load(&snflag[ln], __ATOMIC_ACQUIRE, __HIP_MEMORY_SCOPE_WORKGROUP)
                    : tu;
                if (__all(f >= tu)) break;
            }
            if (ln >= 16 && ln < 16 + SU) {            // 11 lanes: s units
                const int j  = ln - 16;
                const int b0 = 3 * j;
                const int b1 = (3 * j + 1 < 32) ? 3 * j + 1 : 31;
                const int b2 = (3 * j + 2 < 32) ? 3 * j + 2 : 31;
                f32x4 v;
                v.x = snew_lds[b0]; v.y = snew_lds[b1]; v.z = snew_lds[b2]; v.w = tagf;
                float* dst = sx + (((size_t)cur * NBLK + blk) * SUS + j) * 4;
                asm volatile("global_store_dwordx4 %0, %1, off sc0 sc1"
                             :: "v"(dst), "v"(v) : "memory");
            }
            if (ln < YU) {                             // 8 lanes: y partial units
                float a0 = 0.0f, a1 = 0.0f;
                #pragma unroll
                for (int r = 0; r < ROWS; ++r) {
                    const float2 w = *(const float2*)&wout_lds[r][2 * ln];
                    a0 += w.x * snew_lds[r];
                    a1 += w.y * snew_lds[r];
                }
                f32x4 v; v.x = a0; v.y = a1; v.z = tagf; v.w = 0.0f;
                float* dst = yx + (((size_t)cur * NBLK + blk) * YU + ln) * 4;
                asm volatile("global_store_dwordx4 %0, %1, off sc0 sc1"
                             :: "v"(dst), "v"(v) : "memory");
            }
            if (ln >= 32 && ln < 40) {                 // 8 lanes: out_s (write-only)
                const int j = ln - 32;
                *(f32x4*)(out_s + (size_t)t * HDIM + rbase + j * 4) =
                    *(const f32x4*)&snew_lds[j * 4];
            }
        } else if (wv == 1) {
            // ---- y-reduce: poll all 128 producers' tagged units, butterfly ----
            if (t + 1 < TSTEPS) x_lds[nxt][ln] = X[(size_t)(t + 1) * IDIM + ln];
            const int u  = ln & 7;
            const int pg = ln >> 3;                    // 8 producer groups of 16
            const float* yb = yx + (size_t)cur * NBLK * YU * 4;
            f32x4 w0,w1,w2,w3,w4,w5,w6,w7,w8,w9,w10,w11,w12,w13,w14,w15;
            for (;;) {
                #define YL(i) asm volatile("global_load_dwordx4 %0, %1, off sc0 sc1" \
                    : "=v"(w##i) : "v"(yb + (((pg << 4) + i) * YU + u) * 4));
                YL(0) YL(1) YL(2) YL(3) YL(4) YL(5) YL(6) YL(7)
                YL(8) YL(9) YL(10) YL(11) YL(12) YL(13) YL(14) YL(15)
                #undef YL
                asm volatile("s_waitcnt vmcnt(0)" ::: "memory");
                __builtin_amdgcn_sched_barrier(0);
                bool ok = __float_as_uint(w0.z) == tu  && __float_as_uint(w1.z) == tu
                       && __float_as_uint(w2.z) == tu  && __float_as_uint(w3.z) == tu
                       && __float_as_uint(w4.z) == tu  && __float_as_uint(w5.z) == tu
                       && __float_as_uint(w6.z) == tu  && __float_as_uint(w7.z) == tu
                       && __float_as_uint(w8.z) == tu  && __float_as_uint(w9.z) == tu
                       && __float_as_uint(w10.z) == tu && __float_as_uint(w11.z) == tu
                       && __float_as_uint(w12.z) == tu && __float_as_uint(w13.z) == tu
                       && __float_as_uint(w14.z) == tu && __float_as_uint(w15.z) == tu;
                if (__all(ok)) break;
            }
            float acc0 = ((w0.x + w1.x) + (w2.x + w3.x)) + ((w4.x + w5.x) + (w6.x + w7.x))
                       + ((w8.x + w9.x) + (w10.x + w11.x)) + ((w12.x + w13.x) + (w14.x + w15.x));
            float acc1 = ((w0.y + w1.y) + (w2.y + w3.y)) + ((w4.y + w5.y) + (w6.y + w7.y))
                       + ((w8.y + w9.y) + (w10.y + w11.y)) + ((w12.y + w13.y) + (w14.y + w15.y));
            acc0 += __shfl_xor(acc0, 8);  acc1 += __shfl_xor(acc1, 8);
            acc0 += __shfl_xor(acc0, 16); acc1 += __shfl_xor(acc1, 16);
            acc0 += __shfl_xor(acc0, 32); acc1 += __shfl_xor(acc1, 32);
            if (ln < 8) {
                if (t + 1 < TSTEPS) { y_lds[nxt][2 * u] = acc0; y_lds[nxt][2 * u + 1] = acc1; }
                if (blk == 0) {
                    out_res[(size_t)t * ODIM + 2 * u]     = acc0;
                    out_res[(size_t)t * ODIM + 2 * u + 1] = acc1;
                }
            }
        } else {
            // ---- s-consumer: poll tagged units, write s_lds[nxt] (overlaps others' compute) ----
            if (t + 1 < TSTEPS) {
                const int wi    = wv - 2;                        // 0..13
                const int start = (wi < 2) ? wi * 10 : 20 + (wi - 2) * 9;
                const int count = (wi < 2) ? 10 : 9;             // 2*10 + 12*9 = 128
                const int U     = count * SU;
                const float* sb = sx + (size_t)cur * NBLK * SUS * 4;
                const int g0 = ln, g1 = ln + 64;
                const int p0 = g0 / SU, u0 = g0 - p0 * SU;
                const bool h1 = g1 < U;
                const int p1 = g1 / SU, u1 = g1 - p1 * SU;
                const float* a0p = sb + (((start + p0) * SUS) + u0) * 4;
                const float* a1p = sb + (((start + p1) * SUS) + u1) * 4;
                f32x4 v0, v1;
                for (;;) {
                    asm volatile("global_load_dwordx4 %0, %1, off sc0 sc1"
                                 : "=v"(v0) : "v"(a0p));
                    if (h1)
                        asm volatile("global_load_dwordx4 %0, %1, off sc0 sc1"
                                     : "=v"(v1) : "v"(a1p));
                    asm volatile("s_waitcnt vmcnt(0)" ::: "memory");
                    __builtin_amdgcn_sched_barrier(0);
                    bool ok = (__float_as_uint(v0.w) == tu) &&
                              (!h1 || __float_as_uint(v1.w) == tu);
                    if (__all(ok)) break;
                }
                float* sd = s_lds[nxt];
                {
                    const int c0 = (start + p0) * 32 + u0 * 3;
                    sd[c0] = v0.x; sd[c0 + 1] = v0.y;
                    if (u0 != SU - 1) sd[c0 + 2] = v0.z;
                }
                if (h1) {
                    const int c1 = (start + p1) * 32 + u1 * 3;
                    sd[c1] = v1.x; sd[c1 + 1] = v1.y;
                    if (u1 != SU - 1) sd[c1 + 2] = v1.z;
                }
            }
        }
        __syncthreads();   // A-sync: s/x/y for t+1 ready
    }
}

extern "C" void kernel_launch(void* const* d_in, const int* in_sizes, int n_in,
                              void* d_out, int out_size, void* d_ws, size_t ws_size,
                              hipStream_t stream) {
    (void)in_sizes; (void)n_in; (void)out_size; (void)ws_size;
    const float* X    = (const float*)d_in[0];
    const float* Win  = (const float*)d_in[1];
    const float* Wres = (const float*)d_in[2];
    const float* b    = (const float*)d_in[3];
    const float* Wfb  = (const float*)d_in[4];
    const float* Wout = (const float*)d_in[5];
    float* out = (float*)d_out;
    float* sx  = (float*)d_ws;                          // 2*128*12*16B = 48 KiB
    float* yx  = (float*)d_ws + 2 * NBLK * SUS * 4;     // 2*128*8*16B  = 32 KiB

    const int words = (2 * NBLK * SUS + 2 * NBLK * YU) * 4;
    init_ws<<<(words + 255) / 256, 256, 0, stream>>>((float*)d_ws);
    esn_kernel<<<NBLK, BLOCK, 0, stream>>>(X, Win, Wres, b, Wfb, Wout, out, sx, yx);
}

// Round 14
// 19463.869 us; speedup vs baseline: 1.2269x; 1.1009x over previous
//
#include <hip/hip_runtime.h>
#include <cstdint>

#define NBLK 128
#define BLOCK 1024
#define ROWS 32            // hidden rows per block: 128*32 = 4096
#define HDIM 4096
#define IDIM 64
#define ODIM 16
#define TSTEPS 4096
#define PAD 576            // 18 groups * 32 slots (bank-dealt ELL)
#define GMAX 18
#define LEAK 0.9f
#define SUN 16             // s units per producer: one per wave {s_2w, s_2w+1, spare, tag}
#define YU 8               // y units per producer: 2 vals + tag + pad
#define SPAD 34            // padded words per 32-value producer chunk in s_lds

typedef float f32x4 __attribute__((ext_vector_type(4)));

// zero the tagged-exchange region every launch (tags use ==, so 0/poison never match)
__global__ void init_ws(float* ws) {
    int i = blockIdx.x * blockDim.x + threadIdx.x;
    if (i < (2 * NBLK * SUN + 2 * NBLK * YU) * 4) ws[i] = 0.0f;
}

__global__ __launch_bounds__(BLOCK) void esn_kernel(
    const float* __restrict__ X,     // [T][I]
    const float* __restrict__ Win,   // [H][I]
    const float* __restrict__ Wres,  // [H][H]
    const float* __restrict__ bvec,  // [H]
    const float* __restrict__ Wfb,   // [H][O]
    const float* __restrict__ Wout,  // [O][H]
    float* __restrict__ out,         // results [T][O] then outputs [T][H]
    float* __restrict__ sx,          // [2][NBLK][SUN] tagged f32x4 units (s exchange)
    float* __restrict__ yx)          // [2][NBLK][YU]  tagged f32x4 units (y partials)
{
    __shared__ float          ell_val[ROWS][PAD];       // 73728 B
    __shared__ unsigned short ell_idx[ROWS][PAD];       // 36864 B (stores PADDED idx)
    __shared__ __align__(16) float s_lds[2][NBLK*SPAD]; // 34816 B (bank-padded chunks)
    __shared__ float          win_lds[ROWS][IDIM];      //  8192 B
    __shared__ float          wfb_lds[ROWS][ODIM];      //  2048 B
    __shared__ __align__(8)  float wout_lds[ROWS][ODIM];//  2048 B ([r][o])
    __shared__ float          b_lds[ROWS];
    __shared__ float          x_lds[IDIM];
    __shared__ float          y_lds[ODIM];
    __shared__ __align__(16) float snew_lds[ROWS];
    __shared__ int            nnz_lds[ROWS];
    __shared__ int            rnds_lds[ROWS];
    __shared__ unsigned char  bankCnt[ROWS][32];        // build only
    __shared__ unsigned char  grpCnt[ROWS][GMAX];       // build only

    const int tid   = threadIdx.x;
    const int blk   = blockIdx.x;
    const int rbase = blk * ROWS;
    const int rowB  = tid >> 5;        // 0..31
    const int lB    = tid & 31;
    const int wv    = tid >> 6;        // 0..15
    const int ln    = tid & 63;

    // ---- pass 0: zero ELL + counters ----
    for (int i = tid; i < ROWS * PAD; i += BLOCK) {
        ell_val[i / PAD][i % PAD] = 0.0f;
        ell_idx[i / PAD][i % PAD] = 0;
    }
    for (int i = tid; i < ROWS * 32; i += BLOCK) bankCnt[i >> 5][i & 31] = 0;
    for (int i = tid; i < ROWS * GMAX; i += BLOCK) grpCnt[i / GMAX][i % GMAX] = 0;

    // ---- pass 1 (parallel): nnz per row ----
    for (int rr = wv * 2; rr < wv * 2 + 2; ++rr) {
        const float* wrow = Wres + (size_t)(rbase + rr) * HDIM;
        int cnt = 0;
        for (int c0 = 0; c0 < HDIM; c0 += 64)
            cnt += __popcll(__ballot(wrow[c0 + ln] != 0.0f));
        if (ln == 0) {
            int nz = cnt < PAD ? cnt : PAD;
            nnz_lds[rr] = nz;
            int gu = (nz + 31) >> 5;
            if (gu < 1) gu = 1;
            if (gu > GMAX) gu = GMAX;
            rnds_lds[rr] = (gu + 1) >> 1;
        }
    }
    __syncthreads();

    // ---- pass 2 (serial per row, deterministic): bank-balanced deal on PADDED banks ----
    if (ln == 0 || ln == 32) {
        const int row = wv * 2 + (ln >> 5);
        const int nz  = nnz_lds[row];
        int gu = (nz + 31) >> 5;
        if (gu < 1) gu = 1;
        if (gu > GMAX) gu = GMAX;
        const float* wrow = Wres + (size_t)(rbase + row) * HDIM;
        int placed = 0;
        for (int c = 0; c < HDIM && placed < nz; ++c) {
            const float w = wrow[c];
            if (w != 0.0f) {
                const int pidx = c + 2 * (c >> 5);       // padded word index (SPAD=34)
                const int b = pidx & 31;                 // bank of the padded gather
                const int r = bankCnt[row][b];
                bankCnt[row][b] = (unsigned char)(r + 1);
                int g = r % gu;
                int p = grpCnt[row][g];
                int guard = 0;
                while (p >= 32 && guard < GMAX) {
                    g = (g + 1 == gu) ? 0 : g + 1;
                    p = grpCnt[row][g];
                    ++guard;
                }
                if (p >= 32) break;
                grpCnt[row][g] = (unsigned char)(p + 1);
                const int slot = ((g >> 1) << 6) + 2 * p + (g & 1);
                ell_val[row][slot] = w;
                ell_idx[row][slot] = (unsigned short)pidx;
                ++placed;
            }
        }
    }

    // ---- small weights into LDS ----
    for (int i = tid; i < ROWS * IDIM; i += BLOCK)
        win_lds[i >> 6][i & 63] = Win[(size_t)(rbase + (i >> 6)) * IDIM + (i & 63)];
    for (int i = tid; i < ROWS * ODIM; i += BLOCK)
        wfb_lds[i >> 4][i & 15] = Wfb[(size_t)(rbase + (i >> 4)) * ODIM + (i & 15)];
    for (int i = tid; i < ROWS * ODIM; i += BLOCK)   // [r][o] = Wout[o][rbase+r]
        wout_lds[i >> 4][i & 15] = Wout[(size_t)(i & 15) * HDIM + rbase + (i >> 4)];
    if (tid < ROWS) b_lds[tid] = bvec[rbase + tid];

    // ---- prologue: s_{-1}=0 (both buffers incl. pad words, flat), y_{-1}=0, x_0 ----
    {
        float* sz = &s_lds[0][0];
        for (int i = tid; i < 2 * NBLK * SPAD; i += BLOCK) sz[i] = 0.0f;
    }
    if (tid < ODIM) y_lds[tid] = 0.0f;
    if (tid >= 64 && tid < 128) x_lds[tid - 64] = X[tid - 64];
    __syncthreads();

    float* out_res = out;
    float* out_s   = out + (size_t)TSTEPS * ODIM;
    const int RB = rnds_lds[rowB];

    for (int t = 0; t < TSTEPS; ++t) {
        const unsigned tu = (unsigned)(t + 1);
        const float tagf = __uint_as_float(tu);
        const int cur = t & 1, nxt = cur ^ 1;

        // ---- phase B: pre = Wres@s + Win@x + Wfb@y + b ; s_new; INLINE unit publish ----
        {
            const float* sc = s_lds[cur];
            float a0 = 0.0f, a1 = 0.0f;
            for (int k = 0; k < RB; ++k) {
                const int e = (k << 6) + (lB << 1);
                const float2  v  = *(const float2*)&ell_val[rowB][e];
                const ushort2 ix = *(const ushort2*)&ell_idx[rowB][e];  // padded idx
                a0 += v.x * sc[ix.x];
                a1 += v.y * sc[ix.y];
            }
            float acc = a0 + a1;
            acc += win_lds[rowB][lB] * x_lds[lB] + win_lds[rowB][lB + 32] * x_lds[lB + 32];
            if (lB < ODIM) acc += wfb_lds[rowB][lB] * y_lds[lB];
            acc += __shfl_xor(acc, 16, 32);
            acc += __shfl_xor(acc, 8, 32);
            acc += __shfl_xor(acc, 4, 32);
            acc += __shfl_xor(acc, 2, 32);
            acc += __shfl_xor(acc, 1, 32);
            float sn = 0.0f;
            if (lB == 0) {
                const float pre = acc + b_lds[rowB];
                sn = (1.0f - LEAK) * sc[blk * SPAD + rowB] + LEAK * tanhf(pre);
                snew_lds[rowB] = sn;
            }
            const float sn1 = __shfl(sn, 32);          // lane 0 gets row 2w+1's value
            if (ln == 0) {
                f32x4 v; v.x = sn; v.y = sn1; v.z = 0.0f; v.w = tagf;   // TAG IN .w
                float* dst = sx + (((size_t)cur * NBLK + blk) * SUN + wv) * 4;
                asm volatile("global_store_dwordx4 %0, %1, off sc0 sc1"
                             :: "v"(dst), "v"(v) : "memory");
                float2 o2; o2.x = sn; o2.y = sn1;      // out_s (plain cached store)
                *(float2*)(out_s + (size_t)t * HDIM + rbase + 2 * wv) = o2;
            }
        }
        __syncthreads();   // B-sync: snew ready; units already in flight

        if (wv == 0) {
            // ---- y publisher: 8 lanes, one {2val,tag} unit each (tag in .z, matches poll) ----
            if (ln < YU) {
                float a0 = 0.0f, a1 = 0.0f;
                #pragma unroll
                for (int r = 0; r < ROWS; ++r) {
                    const float2 w = *(const float2*)&wout_lds[r][2 * ln];
                    a0 += w.x * snew_lds[r];
                    a1 += w.y * snew_lds[r];
                }
                f32x4 v; v.x = a0; v.y = a1; v.z = tagf; v.w = 0.0f;
                float* dst = yx + (((size_t)cur * NBLK + blk) * YU + ln) * 4;
                asm volatile("global_store_dwordx4 %0, %1, off sc0 sc1"
                             :: "v"(dst), "v"(v) : "memory");
            }
        } else if (wv == 1) {
            // ---- y-reduce: poll all 128 producers' tagged units, butterfly ----
            if (t + 1 < TSTEPS) x_lds[ln] = X[(size_t)(t + 1) * IDIM + ln];
            const int u  = ln & 7;
            const int pg = ln >> 3;                    // 8 producer groups of 16
            const float* yb = yx + (size_t)cur * NBLK * YU * 4;
            f32x4 w0,w1,w2,w3,w4,w5,w6,w7,w8,w9,w10,w11,w12,w13,w14,w15;
            for (;;) {
                #define YL(i) asm volatile("global_load_dwordx4 %0, %1, off sc0 sc1" \
                    : "=v"(w##i) : "v"(yb + (((pg << 4) + i) * YU + u) * 4));
                YL(0) YL(1) YL(2) YL(3) YL(4) YL(5) YL(6) YL(7)
                YL(8) YL(9) YL(10) YL(11) YL(12) YL(13) YL(14) YL(15)
                #undef YL
                asm volatile("s_waitcnt vmcnt(0)" ::: "memory");
                __builtin_amdgcn_sched_barrier(0);
                bool ok = __float_as_uint(w0.z) == tu  && __float_as_uint(w1.z) == tu
                       && __float_as_uint(w2.z) == tu  && __float_as_uint(w3.z) == tu
                       && __float_as_uint(w4.z) == tu  && __float_as_uint(w5.z) == tu
                       && __float_as_uint(w6.z) == tu  && __float_as_uint(w7.z) == tu
                       && __float_as_uint(w8.z) == tu  && __float_as_uint(w9.z) == tu
                       && __float_as_uint(w10.z) == tu && __float_as_uint(w11.z) == tu
                       && __float_as_uint(w12.z) == tu && __float_as_uint(w13.z) == tu
                       && __float_as_uint(w14.z) == tu && __float_as_uint(w15.z) == tu;
                if (__all(ok)) break;
            }
            float acc0 = ((w0.x + w1.x) + (w2.x + w3.x)) + ((w4.x + w5.x) + (w6.x + w7.x))
                       + ((w8.x + w9.x) + (w10.x + w11.x)) + ((w12.x + w13.x) + (w14.x + w15.x));
            float acc1 = ((w0.y + w1.y) + (w2.y + w3.y)) + ((w4.y + w5.y) + (w6.y + w7.y))
                       + ((w8.y + w9.y) + (w10.y + w11.y)) + ((w12.y + w13.y) + (w14.y + w15.y));
            acc0 += __shfl_xor(acc0, 8);  acc1 += __shfl_xor(acc1, 8);
            acc0 += __shfl_xor(acc0, 16); acc1 += __shfl_xor(acc1, 16);
            acc0 += __shfl_xor(acc0, 32); acc1 += __shfl_xor(acc1, 32);
            if (ln < 8) {
                if (t + 1 < TSTEPS) { y_lds[2 * u] = acc0; y_lds[2 * u + 1] = acc1; }
                if (blk == 0) {
                    out_res[(size_t)t * ODIM + 2 * u]     = acc0;
                    out_res[(size_t)t * ODIM + 2 * u + 1] = acc1;
                }
            }
        } else {
            // ---- s-consumer: poll this wave's slice of per-wave units; padded scatter ----
            if (t + 1 < TSTEPS) {
                const int wi    = wv - 2;                        // 0..13
                const int start = (wi < 2) ? wi * 10 : 20 + (wi - 2) * 9;
                const int count = (wi < 2) ? 10 : 9;             // 2*10 + 12*9 = 128
                const int U     = count * SUN;                   // 160 or 144
                const float* sb = sx + ((size_t)cur * NBLK + start) * SUN * 4;
                const int g0 = ln, g1 = ln + 64, g2 = ln + 128;
                const bool h1 = g1 < U, h2 = g2 < U;
                f32x4 v0, v1, v2;
                for (;;) {
                    asm volatile("global_load_dwordx4 %0, %1, off sc0 sc1"
                                 : "=v"(v0) : "v"(sb + (size_t)g0 * 4));
                    if (h1)
                        asm volatile("global_load_dwordx4 %0, %1, off sc0 sc1"
                                     : "=v"(v1) : "v"(sb + (size_t)g1 * 4));
                    if (h2)
                        asm volatile("global_load_dwordx4 %0, %1, off sc0 sc1"
                                     : "=v"(v2) : "v"(sb + (size_t)g2 * 4));
                    asm volatile("s_waitcnt vmcnt(0)" ::: "memory");
                    __builtin_amdgcn_sched_barrier(0);
                    bool ok = (__float_as_uint(v0.w) == tu)
                           && (!h1 || __float_as_uint(v1.w) == tu)
                           && (!h2 || __float_as_uint(v2.w) == tu);
                    if (__all(ok)) break;
                }
                float* sd = s_lds[nxt];
                {   const int pp = start + (g0 >> 4), u = g0 & 15;
                    float2 s2; s2.x = v0.x; s2.y = v0.y;
                    *(float2*)&sd[pp * SPAD + 2 * u] = s2; }
                if (h1) {
                    const int pp = start + (g1 >> 4), u = g1 & 15;
                    float2 s2; s2.x = v1.x; s2.y = v1.y;
                    *(float2*)&sd[pp * SPAD + 2 * u] = s2; }
                if (h2) {
                    const int pp = start + (g2 >> 4), u = g2 & 15;
                    float2 s2; s2.x = v2.x; s2.y = v2.y;
                    *(float2*)&sd[pp * SPAD + 2 * u] = s2; }
            }
        }
        __syncthreads();   // A-sync: s/x/y for t+1 ready
    }
}

extern "C" void kernel_launch(void* const* d_in, const int* in_sizes, int n_in,
                              void* d_out, int out_size, void* d_ws, size_t ws_size,
                              hipStream_t stream) {
    (void)in_sizes; (void)n_in; (void)out_size; (void)ws_size;
    const float* X    = (const float*)d_in[0];
    const float* Win  = (const float*)d_in[1];
    const float* Wres = (const float*)d_in[2];
    const float* b    = (const float*)d_in[3];
    const float* Wfb  = (const float*)d_in[4];
    const float* Wout = (const float*)d_in[5];
    float* out = (float*)d_out;
    float* sx  = (float*)d_ws;                          // 2*128*16*16B = 64 KiB
    float* yx  = (float*)d_ws + 2 * NBLK * SUN * 4;     // 2*128*8*16B  = 32 KiB

    const int words = (2 * NBLK * SUN + 2 * NBLK * YU) * 4;
    init_ws<<<(words + 255) / 256, 256, 0, stream>>>((float*)d_ws);
    esn_kernel<<<NBLK, BLOCK, 0, stream>>>(X, Win, Wres, b, Wfb, Wout, out, sx, yx);
}

// Round 15
// 18902.722 us; speedup vs baseline: 1.2633x; 1.0297x over previous
//
#include <hip/hip_runtime.h>
#include <cstdint>

#define NBLK 128
#define BLOCK 1024
#define ROWS 32            // hidden rows per block: 128*32 = 4096
#define HDIM 4096
#define IDIM 64
#define ODIM 16
#define TSTEPS 4096
#define PAD 576            // 18 groups * 32 slots (bank-dealt ELL)
#define GMAX 18
#define LEAK 0.9f
#define SUN 16             // s units per producer: one per wave {s_2w, s_2w+1, spare, tag}
#define YU 8               // y units per producer: 2 vals + tag + pad
#define SPAD 34            // padded words per 32-value producer chunk in s_lds

typedef float f32x4 __attribute__((ext_vector_type(4)));

// zero the tagged-exchange region every launch (tags use ==, so 0/poison never match)
__global__ void init_ws(float* ws) {
    int i = blockIdx.x * blockDim.x + threadIdx.x;
    if (i < (2 * NBLK * SUN + 2 * NBLK * YU) * 4) ws[i] = 0.0f;
}

__global__ __launch_bounds__(BLOCK) void esn_kernel(
    const float* __restrict__ X,     // [T][I]
    const float* __restrict__ Win,   // [H][I]
    const float* __restrict__ Wres,  // [H][H]
    const float* __restrict__ bvec,  // [H]
    const float* __restrict__ Wfb,   // [H][O]
    const float* __restrict__ Wout,  // [O][H]
    float* __restrict__ out,         // results [T][O] then outputs [T][H]
    float* __restrict__ sx,          // [2][NBLK][SUN] tagged f32x4 units (s exchange)
    float* __restrict__ yx)          // [2][NBLK][YU]  tagged f32x4 units (y partials)
{
    __shared__ float          ell_val[ROWS][PAD];       // 73728 B
    __shared__ unsigned short ell_idx[ROWS][PAD];       // 36864 B (stores PADDED idx)
    __shared__ __align__(16) float s_lds[2][NBLK*SPAD]; // 34816 B (bank-padded chunks)
    __shared__ float          win_lds[ROWS][IDIM];      //  8192 B
    __shared__ float          wfb_lds[ROWS][ODIM];      //  2048 B
    __shared__ __align__(8)  float wout_lds[ROWS][ODIM];//  2048 B ([r][o])
    __shared__ float          b_lds[ROWS];
    __shared__ float          x_lds[2][IDIM];           //  512 B (double buffer)
    __shared__ float          y_lds[2][ODIM];           //  128 B (double buffer)
    __shared__ __align__(8)  float ytmp[16][18];        //  1152 B (per-wave y contribs, padded)
    __shared__ unsigned       done[16];                 // per-wave phase-B completion (LDS)
    __shared__ int            nnz_lds[ROWS];
    __shared__ int            rnds_lds[ROWS];
    __shared__ unsigned char  bankCnt[ROWS][32];        // build only
    __shared__ unsigned char  grpCnt[ROWS][GMAX];       // build only

    const int tid   = threadIdx.x;
    const int blk   = blockIdx.x;
    const int rbase = blk * ROWS;
    const int rowB  = tid >> 5;        // 0..31
    const int lB    = tid & 31;
    const int wv    = tid >> 6;        // 0..15
    const int ln    = tid & 63;

    // ---- pass 0: zero ELL + counters ----
    for (int i = tid; i < ROWS * PAD; i += BLOCK) {
        ell_val[i / PAD][i % PAD] = 0.0f;
        ell_idx[i / PAD][i % PAD] = 0;
    }
    for (int i = tid; i < ROWS * 32; i += BLOCK) bankCnt[i >> 5][i & 31] = 0;
    for (int i = tid; i < ROWS * GMAX; i += BLOCK) grpCnt[i / GMAX][i % GMAX] = 0;
    if (tid < 16) done[tid] = 0u;

    // ---- pass 1 (parallel): nnz per row ----
    for (int rr = wv * 2; rr < wv * 2 + 2; ++rr) {
        const float* wrow = Wres + (size_t)(rbase + rr) * HDIM;
        int cnt = 0;
        for (int c0 = 0; c0 < HDIM; c0 += 64)
            cnt += __popcll(__ballot(wrow[c0 + ln] != 0.0f));
        if (ln == 0) {
            int nz = cnt < PAD ? cnt : PAD;
            nnz_lds[rr] = nz;
            int gu = (nz + 31) >> 5;
            if (gu < 1) gu = 1;
            if (gu > GMAX) gu = GMAX;
            rnds_lds[rr] = (gu + 1) >> 1;
        }
    }
    __syncthreads();

    // ---- pass 2 (serial per row, deterministic): bank-balanced deal on PADDED banks ----
    if (ln == 0 || ln == 32) {
        const int row = wv * 2 + (ln >> 5);
        const int nz  = nnz_lds[row];
        int gu = (nz + 31) >> 5;
        if (gu < 1) gu = 1;
        if (gu > GMAX) gu = GMAX;
        const float* wrow = Wres + (size_t)(rbase + row) * HDIM;
        int placed = 0;
        for (int c = 0; c < HDIM && placed < nz; ++c) {
            const float w = wrow[c];
            if (w != 0.0f) {
                const int pidx = c + 2 * (c >> 5);       // padded word index (SPAD=34)
                const int b = pidx & 31;                 // bank of the padded gather
                const int r = bankCnt[row][b];
                bankCnt[row][b] = (unsigned char)(r + 1);
                int g = r % gu;
                int p = grpCnt[row][g];
                int guard = 0;
                while (p >= 32 && guard < GMAX) {
                    g = (g + 1 == gu) ? 0 : g + 1;
                    p = grpCnt[row][g];
                    ++guard;
                }
                if (p >= 32) break;
                grpCnt[row][g] = (unsigned char)(p + 1);
                const int slot = ((g >> 1) << 6) + 2 * p + (g & 1);
                ell_val[row][slot] = w;
                ell_idx[row][slot] = (unsigned short)pidx;
                ++placed;
            }
        }
    }

    // ---- small weights into LDS ----
    for (int i = tid; i < ROWS * IDIM; i += BLOCK)
        win_lds[i >> 6][i & 63] = Win[(size_t)(rbase + (i >> 6)) * IDIM + (i & 63)];
    for (int i = tid; i < ROWS * ODIM; i += BLOCK)
        wfb_lds[i >> 4][i & 15] = Wfb[(size_t)(rbase + (i >> 4)) * ODIM + (i & 15)];
    for (int i = tid; i < ROWS * ODIM; i += BLOCK)   // [r][o] = Wout[o][rbase+r]
        wout_lds[i >> 4][i & 15] = Wout[(size_t)(i & 15) * HDIM + rbase + (i >> 4)];
    if (tid < ROWS) b_lds[tid] = bvec[rbase + tid];

    // ---- prologue: s_{-1}=0 (both buffers, flat), y_{-1}=0, x_0 ----
    {
        float* sz = &s_lds[0][0];
        for (int i = tid; i < 2 * NBLK * SPAD; i += BLOCK) sz[i] = 0.0f;
    }
    if (tid < ODIM) y_lds[0][tid] = 0.0f;
    if (tid >= 64 && tid < 128) x_lds[0][tid - 64] = X[tid - 64];
    __syncthreads();

    float* out_res = out;
    float* out_s   = out + (size_t)TSTEPS * ODIM;
    const int RB = rnds_lds[rowB];

    for (int t = 0; t < TSTEPS; ++t) {
        const unsigned tu = (unsigned)(t + 1);
        const float tagf = __uint_as_float(tu);
        const int cur = t & 1, nxt = cur ^ 1;

        // ---- phase B: gather, reduce; per-wave INLINE publish of s-unit + y-contrib ----
        {
            const float* sc = s_lds[cur];
            float a0 = 0.0f, a1 = 0.0f;
            for (int k = 0; k < RB; ++k) {
                const int e = (k << 6) + (lB << 1);
                const float2  v  = *(const float2*)&ell_val[rowB][e];
                const ushort2 ix = *(const ushort2*)&ell_idx[rowB][e];  // padded idx
                a0 += v.x * sc[ix.x];
                a1 += v.y * sc[ix.y];
            }
            float acc = a0 + a1;
            acc += win_lds[rowB][lB] * x_lds[cur][lB]
                 + win_lds[rowB][lB + 32] * x_lds[cur][lB + 32];
            if (lB < ODIM) acc += wfb_lds[rowB][lB] * y_lds[cur][lB];
            acc += __shfl_xor(acc, 16, 32);
            acc += __shfl_xor(acc, 8, 32);
            acc += __shfl_xor(acc, 4, 32);
            acc += __shfl_xor(acc, 2, 32);
            acc += __shfl_xor(acc, 1, 32);
            // all lanes of each 32-half now hold the row sum
            const float pre = acc + b_lds[rowB];
            const float snAll = (1.0f - LEAK) * sc[blk * SPAD + rowB] + LEAK * tanhf(pre);
            const float sn0 = __shfl(snAll, 0);    // row 2w
            const float sn1 = __shfl(snAll, 32);   // row 2w+1
            if (ln < 16)                           // wave's y contribution (order = r asc)
                ytmp[wv][ln] = wout_lds[2 * wv][ln] * sn0 + wout_lds[2 * wv + 1][ln] * sn1;
            if (ln == 0) {
                f32x4 v; v.x = sn0; v.y = sn1; v.z = 0.0f; v.w = tagf;   // tag in .w
                float* dst = sx + (((size_t)cur * NBLK + blk) * SUN + wv) * 4;
                asm volatile("global_store_dwordx4 %0, %1, off sc0 sc1"
                             :: "v"(dst), "v"(v) : "memory");
                float2 o2; o2.x = sn0; o2.y = sn1;   // out_s (plain cached store)
                *(float2*)(out_s + (size_t)t * HDIM + rbase + 2 * wv) = o2;
                __hip_atomic_store(&done[wv], tu, __ATOMIC_RELEASE,
                                   __HIP_MEMORY_SCOPE_WORKGROUP);  // orders ytmp writes
            }
        }
        // NO B-sync: waves proceed straight to their exchange roles.

        if (wv == 0) {
            // ---- y publisher: wait 16 LDS flags (cheap), sum ytmp, publish units ----
            for (;;) {
                unsigned f = (ln < 16)
                    ? __hip_atomic_load(&done[ln], __ATOMIC_ACQUIRE, __HIP_MEMORY_SCOPE_WORKGROUP)
                    : tu;
                if (__all(f >= tu)) break;
            }
            if (ln < YU) {
                float a0 = 0.0f, a1 = 0.0f;
                #pragma unroll
                for (int w = 0; w < 16; ++w) {       // order = w asc = r asc
                    const float2 p = *(const float2*)&ytmp[w][2 * ln];
                    a0 += p.x;
                    a1 += p.y;
                }
                f32x4 v; v.x = a0; v.y = a1; v.z = tagf; v.w = 0.0f;   // tag in .z
                float* dst = yx + (((size_t)cur * NBLK + blk) * YU + ln) * 4;
                asm volatile("global_store_dwordx4 %0, %1, off sc0 sc1"
                             :: "v"(dst), "v"(v) : "memory");
            }
        } else if (wv == 1) {
            // ---- y-reduce: x[nxt] prefetch; poll all 128 y units; butterfly ----
            if (t + 1 < TSTEPS) x_lds[nxt][ln] = X[(size_t)(t + 1) * IDIM + ln];
            const int u  = ln & 7;
            const int pg = ln >> 3;                    // 8 producer groups of 16
            const float* yb = yx + (size_t)cur * NBLK * YU * 4;
            f32x4 w0,w1,w2,w3,w4,w5,w6,w7,w8,w9,w10,w11,w12,w13,w14,w15;
            for (;;) {
                #define YL(i) asm volatile("global_load_dwordx4 %0, %1, off sc0 sc1" \
                    : "=v"(w##i) : "v"(yb + (((pg << 4) + i) * YU + u) * 4));
                YL(0) YL(1) YL(2) YL(3) YL(4) YL(5) YL(6) YL(7)
                YL(8) YL(9) YL(10) YL(11) YL(12) YL(13) YL(14) YL(15)
                #undef YL
                asm volatile("s_waitcnt vmcnt(0)" ::: "memory");
                __builtin_amdgcn_sched_barrier(0);
                bool ok = __float_as_uint(w0.z) == tu  && __float_as_uint(w1.z) == tu
                       && __float_as_uint(w2.z) == tu  && __float_as_uint(w3.z) == tu
                       && __float_as_uint(w4.z) == tu  && __float_as_uint(w5.z) == tu
                       && __float_as_uint(w6.z) == tu  && __float_as_uint(w7.z) == tu
                       && __float_as_uint(w8.z) == tu  && __float_as_uint(w9.z) == tu
                       && __float_as_uint(w10.z) == tu && __float_as_uint(w11.z) == tu
                       && __float_as_uint(w12.z) == tu && __float_as_uint(w13.z) == tu
                       && __float_as_uint(w14.z) == tu && __float_as_uint(w15.z) == tu;
                if (__all(ok)) break;
            }
            float acc0 = ((w0.x + w1.x) + (w2.x + w3.x)) + ((w4.x + w5.x) + (w6.x + w7.x))
                       + ((w8.x + w9.x) + (w10.x + w11.x)) + ((w12.x + w13.x) + (w14.x + w15.x));
            float acc1 = ((w0.y + w1.y) + (w2.y + w3.y)) + ((w4.y + w5.y) + (w6.y + w7.y))
                       + ((w8.y + w9.y) + (w10.y + w11.y)) + ((w12.y + w13.y) + (w14.y + w15.y));
            acc0 += __shfl_xor(acc0, 8);  acc1 += __shfl_xor(acc1, 8);
            acc0 += __shfl_xor(acc0, 16); acc1 += __shfl_xor(acc1, 16);
            acc0 += __shfl_xor(acc0, 32); acc1 += __shfl_xor(acc1, 32);
            if (ln < 8) {
                if (t + 1 < TSTEPS) { y_lds[nxt][2 * u] = acc0; y_lds[nxt][2 * u + 1] = acc1; }
                if (blk == 0) {
                    out_res[(size_t)t * ODIM + 2 * u]     = acc0;
                    out_res[(size_t)t * ODIM + 2 * u + 1] = acc1;
                }
            }
        } else {
            // ---- s-consumer: poll this wave's slice of per-wave units; padded scatter ----
            if (t + 1 < TSTEPS) {
                const int wi    = wv - 2;                        // 0..13
                const int start = (wi < 2) ? wi * 10 : 20 + (wi - 2) * 9;
                const int count = (wi < 2) ? 10 : 9;             // 2*10 + 12*9 = 128
                const int U     = count * SUN;                   // 160 or 144
                const float* sb = sx + ((size_t)cur * NBLK + start) * SUN * 4;
                const int g0 = ln, g1 = ln + 64, g2 = ln + 128;
                const bool h1 = g1 < U, h2 = g2 < U;
                f32x4 v0, v1, v2;
                for (;;) {
                    asm volatile("global_load_dwordx4 %0, %1, off sc0 sc1"
                                 : "=v"(v0) : "v"(sb + (size_t)g0 * 4));
                    if (h1)
                        asm volatile("global_load_dwordx4 %0, %1, off sc0 sc1"
                                     : "=v"(v1) : "v"(sb + (size_t)g1 * 4));
                    if (h2)
                        asm volatile("global_load_dwordx4 %0, %1, off sc0 sc1"
                                     : "=v"(v2) : "v"(sb + (size_t)g2 * 4));
                    asm volatile("s_waitcnt vmcnt(0)" ::: "memory");
                    __builtin_amdgcn_sched_barrier(0);
                    bool ok = (__float_as_uint(v0.w) == tu)
                           && (!h1 || __float_as_uint(v1.w) == tu)
                           && (!h2 || __float_as_uint(v2.w) == tu);
                    if (__all(ok)) break;
                }
                float* sd = s_lds[nxt];
                {   const int pp = start + (g0 >> 4), u = g0 & 15;
                    float2 s2; s2.x = v0.x; s2.y = v0.y;
                    *(float2*)&sd[pp * SPAD + 2 * u] = s2; }
                if (h1) {
                    const int pp = start + (g1 >> 4), u = g1 & 15;
                    float2 s2; s2.x = v1.x; s2.y = v1.y;
                    *(float2*)&sd[pp * SPAD + 2 * u] = s2; }
                if (h2) {
                    const int pp = start + (g2 >> 4), u = g2 & 15;
                    float2 s2; s2.x = v2.x; s2.y = v2.y;
                    *(float2*)&sd[pp * SPAD + 2 * u] = s2; }
            }
        }
        __syncthreads();   // A-sync: s/x/y for t+1 ready; gates exchange-buffer reuse
    }
}

extern "C" void kernel_launch(void* const* d_in, const int* in_sizes, int n_in,
                              void* d_out, int out_size, void* d_ws, size_t ws_size,
                              hipStream_t stream) {
    (void)in_sizes; (void)n_in; (void)out_size; (void)ws_size;
    const float* X    = (const float*)d_in[0];
    const float* Win  = (const float*)d_in[1];
    const float* Wres = (const float*)d_in[2];
    const float* b    = (const float*)d_in[3];
    const float* Wfb  = (const float*)d_in[4];
    const float* Wout = (const float*)d_in[5];
    float* out = (float*)d_out;
    float* sx  = (float*)d_ws;                          // 2*128*16*16B = 64 KiB
    float* yx  = (float*)d_ws + 2 * NBLK * SUN * 4;     // 2*128*8*16B  = 32 KiB

    const int words = (2 * NBLK * SUN + 2 * NBLK * YU) * 4;
    init_ws<<<(words + 255) / 256, 256, 0, stream>>>((float*)d_ws);
    esn_kernel<<<NBLK, BLOCK, 0, stream>>>(X, Win, Wres, b, Wfb, Wout, out, sx, yx);
}